// Round 4
// baseline (254.350 us; speedup 1.0000x reference)
//
#include <hip/hip_runtime.h>

typedef unsigned short u16;
typedef unsigned int   u32;
typedef unsigned long long u64;

typedef __attribute__((ext_vector_type(8))) short bf16x8;
typedef __attribute__((ext_vector_type(4))) float f32x4;

#define BB 4
#define MM 2048
#define NN 16384
#define DD 64

__device__ __forceinline__ u16 f2bf(float f) {
    union { float f; u32 u; } v; v.f = f;
    u32 r = v.u + 0x7fffu + ((v.u >> 16) & 1u);   // RNE
    return (u16)(r >> 16);
}

// pack two floats to bf16 pair by truncation: lo16=trunc(lo), hi16=trunc(hi)
__device__ __forceinline__ u32 pack_trunc(float hi, float lo) {
    union { float f; u32 u; } a, b; a.f = hi; b.f = lo;
    return __builtin_amdgcn_perm(a.u, b.u, 0x07060302);
}

// RNE pack of two floats into a bf16 pair
__device__ __forceinline__ u32 pack_rne(float hi, float lo) {
    return (u32)f2bf(lo) | ((u32)f2bf(hi) << 16);
}

__device__ __forceinline__ bf16x8 pack8(float4 p, float4 q) {
    bf16x8 v;
    v[0] = (short)f2bf(p.x); v[1] = (short)f2bf(p.y);
    v[2] = (short)f2bf(p.z); v[3] = (short)f2bf(p.w);
    v[4] = (short)f2bf(q.x); v[5] = (short)f2bf(q.y);
    v[6] = (short)f2bf(q.z); v[7] = (short)f2bf(q.w);
    return v;
}

// ===========================================================================
// ws layout (v2/v3 path):
//   [0, 8M)        interp bf16 [b][n][64]
//   [8M, 9M)       fdT   bf16 [b][d][m]   (feat_down transposed)
//   [9M, +128K)    xyzd2 float4 [b*M]  = (-2bx,-2by,-2bz, |b|^2+1e-8)
//   [.., +32K)     W1 bf16 [128][128]
//   [.., +16K)     W2 bf16 [64][128]
//   [.., +1.5K)    bn consts float[384] = A1[128] Bc1[128] A2[64] Bc2[64]
// ===========================================================================
#define OFF_INTERP 0ull
#define OFF_FDT    8388608ull
#define OFF_XYZ    9437184ull
#define OFF_W1     9568256ull
#define OFF_W2     9601024ull
#define OFF_BN     9617408ull
#define WS_NEED    9618944ull

// ---------------------------------------------------------------------------
// prep3: coalesced LDS-tile transpose + conversions. 173 blocks x 256.
//  blk   0..127 : feat_down transpose  (b = blk>>5, m-tile = blk&31)
//  blk 128..159 : xyzd2
//  blk 160..167 : W1 -> bf16
//  blk 168..171 : W2 -> bf16
//  blk 172      : BN fold
// ---------------------------------------------------------------------------
__global__ __launch_bounds__(256)
void prep3_kernel(const float* __restrict__ xyz_down,
                  const float* __restrict__ feat_down,
                  const float* __restrict__ W1, const float* __restrict__ b1,
                  const float* __restrict__ g1, const float* __restrict__ be1,
                  const float* __restrict__ m1, const float* __restrict__ v1,
                  const float* __restrict__ W2, const float* __restrict__ b2,
                  const float* __restrict__ g2, const float* __restrict__ be2,
                  const float* __restrict__ m2, const float* __restrict__ v2,
                  u16* __restrict__ fdT, float4* __restrict__ xyzd2,
                  u16* __restrict__ w1bf, u16* __restrict__ w2bf,
                  float* __restrict__ bnbuf)
{
    const int blk = blockIdx.x, t = threadIdx.x;
    if (blk < 128) {
        __shared__ u16 T[64 * 68];                 // [m_local][d], stride 68
        const int b = blk >> 5, m0 = (blk & 31) * 64;
        // phase A: coalesced read, convert, store to LDS rows
        {
            const int row = t >> 2, fcb = (t & 3) * 16;   // 4 threads/row, 16 cols each
            const float4* src = (const float4*)(feat_down + ((size_t)(b * MM + m0 + row)) * 64 + fcb);
#pragma unroll
            for (int i = 0; i < 4; i++) {
                float4 v = src[i];
                union { u16 h[4]; u64 q; } pk;
                pk.h[0] = f2bf(v.x); pk.h[1] = f2bf(v.y);
                pk.h[2] = f2bf(v.z); pk.h[3] = f2bf(v.w);
                *(u64*)&T[row * 68 + fcb + i * 4] = pk.q;
            }
        }
        __syncthreads();
        // phase B: gather column d, write coalesced 32B runs of m
        {
            const int d = t >> 2, ms = (t & 3) * 16;
            union { u16 h[16]; uint4 q[2]; } o;
#pragma unroll
            for (int j = 0; j < 16; j++) o.h[j] = T[(ms + j) * 68 + d];
            uint4* dst = (uint4*)&fdT[((size_t)(b * 64 + d)) * MM + m0 + ms];
            dst[0] = o.q[0];
            dst[1] = o.q[1];
        }
    } else if (blk < 160) {
        int idx = (blk - 128) * 256 + t;           // b*M + m
        float x = xyz_down[idx * 3 + 0], y = xyz_down[idx * 3 + 1], z = xyz_down[idx * 3 + 2];
        xyzd2[idx] = make_float4(-2.f * x, -2.f * y, -2.f * z,
                                 x * x + y * y + z * z + 1e-8f);
    } else if (blk < 168) {
        int g = (blk - 160) * 256 + t;             // group of 8 elems
        const float4* s = (const float4*)(W1 + g * 8);
        bf16x8 v = pack8(s[0], s[1]);
        *(bf16x8*)&w1bf[g * 8] = v;
    } else if (blk < 172) {
        int g = (blk - 168) * 256 + t;
        const float4* s = (const float4*)(W2 + g * 8);
        bf16x8 v = pack8(s[0], s[1]);
        *(bf16x8*)&w2bf[g * 8] = v;
    } else {
        if (t < 128) {
            float a = g1[t] * rsqrtf(v1[t] + 1e-5f);
            bnbuf[t] = a;
            bnbuf[128 + t] = (b1[t] - m1[t]) * a + be1[t];
        } else if (t < 192) {
            int o = t - 128;
            float a = g2[o] * rsqrtf(v2[o] + 1e-5f);
            bnbuf[256 + o] = a;
            bnbuf[320 + o] = (b2[o] - m2[o]) * a + be2[o];
        }
    }
}

// ---------------------------------------------------------------------------
// interp3: barrier-free K-loop. All xyzd2 for the batch staged in LDS once
// (swizzled, broadcast reads); B-fragments (fdT) read straight from global
// (L2-resident, compiler pipelines across chunks — no barriers to drain);
// denominator accumulated via MFMA with an all-ones B-fragment.
// ---------------------------------------------------------------------------
__global__ __launch_bounds__(256, 4)
void interp3_kernel(const float* __restrict__ xyz_up,
                    const u16* __restrict__ fdT,
                    const float4* __restrict__ xyzd2,
                    u16* __restrict__ interp_out)
{
    __shared__ float4 xyzall[MM + MM / 8];   // swizzled: idx = m + (m>>3)

    const int tid = threadIdx.x;
    const int b  = blockIdx.x >> 8;
    const int n0 = (blockIdx.x & 255) * 64;
    const int wave = tid >> 6;
    const int lane = tid & 63;
    const int q    = lane >> 4;
    const int nl   = lane & 15;

    // stage all 2048 xyzd2 entries (8 per thread, coalesced)
#pragma unroll
    for (int i = 0; i < 8; i++) {
        int m = i * 256 + tid;
        xyzall[m + (m >> 3)] = xyzd2[b * MM + m];
    }

    const int row = n0 + wave * 16 + nl;
    const float* xu = xyz_up + ((size_t)(b * NN + row)) * 3;
    const float ax = xu[0], ay = xu[1], az = xu[2];
    const float a2 = ax * ax + ay * ay + az * az;

    f32x4 acc[4];
#pragma unroll
    for (int i = 0; i < 4; i++) acc[i] = (f32x4){0.f, 0.f, 0.f, 0.f};
    f32x4 accd = (f32x4){0.f, 0.f, 0.f, 0.f};

    bf16x8 ones;
#pragma unroll
    for (int i = 0; i < 8; i++) ones[i] = (short)0x3F80;   // bf16 1.0

    const u16* fb = fdT + (size_t)b * 64 * MM;
    __syncthreads();

#pragma unroll 2
    for (int mc = 0; mc < MM; mc += 64) {
        // B-fragments for this chunk straight from global (no LDS round-trip)
        bf16x8 bfr[2][4];
#pragma unroll
        for (int kk = 0; kk < 2; kk++)
#pragma unroll
            for (int dt = 0; dt < 4; dt++)
                bfr[kk][dt] = *(const bf16x8*)(fb + (size_t)(dt * 16 + nl) * MM + mc + kk * 32 + q * 8);

        // r-phase: fp32 dist + rcp, truncate to bf16 pairs in A-frag order
        u32 fr[2][4];
#pragma unroll
        for (int kk = 0; kk < 2; kk++) {
#pragma unroll
            for (int jp = 0; jp < 4; jp++) {
                int m0 = mc + kk * 32 + q * 8 + jp * 2;
                int s0 = m0 + (m0 >> 3);            // m0,m0+1 share the 8-group
                float4 p0 = xyzall[s0];
                float4 p1 = xyzall[s0 + 1];
                float d0 = fmaf(p0.x, ax, fmaf(p0.y, ay, fmaf(p0.z, az, p0.w + a2)));
                float d1 = fmaf(p1.x, ax, fmaf(p1.y, ay, fmaf(p1.z, az, p1.w + a2)));
                d0 = fmaxf(d0, 1e-8f);
                d1 = fmaxf(d1, 1e-8f);
                float r0 = __builtin_amdgcn_rcpf(d0);
                float r1 = __builtin_amdgcn_rcpf(d1);
                fr[kk][jp] = pack_trunc(r1, r0);
            }
        }
#pragma unroll
        for (int kk = 0; kk < 2; kk++) {
            union { u32 u[4]; bf16x8 v; } af;
            af.u[0] = fr[kk][0]; af.u[1] = fr[kk][1];
            af.u[2] = fr[kk][2]; af.u[3] = fr[kk][3];
#pragma unroll
            for (int dt = 0; dt < 4; dt++)
                acc[dt] = __builtin_amdgcn_mfma_f32_16x16x32_bf16(af.v, bfr[kk][dt], acc[dt], 0, 0, 0);
            // den: row-sum of the SAME truncated r (ones B-frag) -> bias cancels
            accd = __builtin_amdgcn_mfma_f32_16x16x32_bf16(af.v, ones, accd, 0, 0, 0);
        }
    }

    // epilogue: accd[reg] holds den for row q*4+reg (identical across cols)
#pragma unroll
    for (int reg = 0; reg < 4; reg++) {
        int r = wave * 16 + q * 4 + reg;
        float inv = 1.0f / accd[reg];
        size_t gbase = ((size_t)(b * NN + n0 + r)) * 64;
#pragma unroll
        for (int dt = 0; dt < 4; dt++)
            interp_out[gbase + dt * 16 + nl] = f2bf(acc[dt][reg] * inv);
    }
}

// ---------------------------------------------------------------------------
// mlp3: W1 staged in LDS (bf16, stride 136 = 16B-aligned rows, 2-way-free
// banks); W2 read from global (16KB, L1-resident during GEMM2). 64 rows/blk.
// ---------------------------------------------------------------------------
__global__ __launch_bounds__(256, 3)
void mlp3_kernel(const float* __restrict__ feat_up,
                 const u16* __restrict__ interp,
                 const u16* __restrict__ w1bf,
                 const u16* __restrict__ w2bf,
                 const float* __restrict__ bnbuf,
                 float* __restrict__ out)
{
    __shared__ u16   w1L[128 * 136];   // 34816 B
    __shared__ u16   hb[64 * 136];     // 17408 B
    __shared__ float bnl[384];         //  1536 B   (total 53760 -> 3 blk/CU)

    const int tid = threadIdx.x;
    const int b  = blockIdx.x >> 8;
    const int n0 = (blockIdx.x & 255) * 64;
    const int wave = tid >> 6;
    const int lane = tid & 63;
    const int q    = lane >> 4;
    const int nl   = lane & 15;

    bnl[tid] = bnbuf[tid];
    if (tid < 128) bnl[256 + tid] = bnbuf[256 + tid];

    // stage W1 -> LDS: thread copies 128B of row o = tid>>1
    {
        const int o = tid >> 1, h = (tid & 1) * 64;
        const uint4* src = (const uint4*)(w1bf + (size_t)o * 128 + h);
        uint4* dst = (uint4*)&w1L[o * 136 + h];
#pragma unroll
        for (int i = 0; i < 8; i++) dst[i] = src[i];
    }

    const int row = n0 + wave * 16 + nl;
    const float* fu = feat_up + ((size_t)(b * NN + row)) * 64;
    const u16*   ip = interp  + ((size_t)(b * NN + row)) * 64;

    f32x4 acc1[8];
#pragma unroll
    for (int i = 0; i < 8; i++) acc1[i] = (f32x4){0.f, 0.f, 0.f, 0.f};
    __syncthreads();

#pragma unroll
    for (int k0 = 0; k0 < 128; k0 += 32) {
        bf16x8 af;
        if (k0 < 64) {
            float4 f0 = *(const float4*)(fu + k0 + q * 8);
            float4 f1 = *(const float4*)(fu + k0 + q * 8 + 4);
            union { u32 u[4]; bf16x8 v; } uu;
            uu.u[0] = pack_rne(f0.y, f0.x);
            uu.u[1] = pack_rne(f0.w, f0.z);
            uu.u[2] = pack_rne(f1.y, f1.x);
            uu.u[3] = pack_rne(f1.w, f1.z);
            af = uu.v;
        } else {
            af = *(const bf16x8*)(ip + (k0 - 64) + q * 8);
        }
#pragma unroll
        for (int ot = 0; ot < 8; ot++) {
            bf16x8 bf = *(const bf16x8*)&w1L[(ot * 16 + nl) * 136 + k0 + q * 8];
            acc1[ot] = __builtin_amdgcn_mfma_f32_16x16x32_bf16(af, bf, acc1[ot], 0, 0, 0);
        }
    }
    // BN1 + ReLU -> bf16 hidden in LDS (transpose to A-layout)
#pragma unroll
    for (int ot = 0; ot < 8; ot++) {
        int o = ot * 16 + nl;
        float aa = bnl[o], bc = bnl[128 + o];
#pragma unroll
        for (int reg = 0; reg < 4; reg++) {
            float v = fmaxf(fmaf(acc1[ot][reg], aa, bc), 0.f);
            hb[(wave * 16 + q * 4 + reg) * 136 + o] = f2bf(v);
        }
    }
    __syncthreads();

    f32x4 acc2[4];
#pragma unroll
    for (int i = 0; i < 4; i++) acc2[i] = (f32x4){0.f, 0.f, 0.f, 0.f};
#pragma unroll
    for (int k0 = 0; k0 < 128; k0 += 32) {
        bf16x8 af = *(bf16x8*)&hb[(wave * 16 + nl) * 136 + k0 + q * 8];
#pragma unroll
        for (int ot = 0; ot < 4; ot++) {
            bf16x8 bf = *(const bf16x8*)(w2bf + (ot * 16 + nl) * 128 + k0 + q * 8);
            acc2[ot] = __builtin_amdgcn_mfma_f32_16x16x32_bf16(af, bf, acc2[ot], 0, 0, 0);
        }
    }
#pragma unroll
    for (int ot = 0; ot < 4; ot++) {
        int o = ot * 16 + nl;
        float aa = bnl[256 + o], bc = bnl[320 + o];
#pragma unroll
        for (int reg = 0; reg < 4; reg++)
            out[((size_t)(b * NN + n0 + wave * 16 + q * 4 + reg)) * 64 + o] =
                fmaf(acc2[ot][reg], aa, bc);
    }
}

// ===========================================================================
// Fallback (round-1 kernels, proven): used when ws_size < WS_NEED.
// ===========================================================================
#define TN 128
#define BM 64
#define RS 72
#define FS 72

__global__ __launch_bounds__(256, 3)
void interp_kernel(const float* __restrict__ xyz_down,
                   const float* __restrict__ xyz_up,
                   const float* __restrict__ feat_down,
                   u16* __restrict__ interp_out)
{
    __shared__ u16   rbuf[TN * RS];
    __shared__ u16   ftbuf[DD * FS];
    __shared__ float xyzb[BM * 3];
    __shared__ float denp[TN * 2];
    __shared__ float invden[TN];

    const int tid = threadIdx.x;
    const int b  = blockIdx.x >> 7;
    const int n0 = (blockIdx.x & 127) * TN;

    const int nl_r = tid >> 1;
    const int half = tid & 1;
    const float* xu = xyz_up + (size_t)(b * NN + n0 + nl_r) * 3;
    const float ax = xu[0], ay = xu[1], az = xu[2];

    denp[tid] = 0.f;

    const int wave = tid >> 6;
    const int lane = tid & 63;
    const int q    = lane >> 4;
    const int nl   = lane & 15;

    f32x4 acc[2][4];
#pragma unroll
    for (int i = 0; i < 2; i++)
#pragma unroll
        for (int j = 0; j < 4; j++) acc[i][j] = (f32x4){0.f, 0.f, 0.f, 0.f};

    const int sm = (tid & 31) * 2;
    const int sd = (tid >> 5) * 8;

    for (int mc = 0; mc < MM; mc += BM) {
        __syncthreads();
        if (tid < 192) xyzb[tid] = xyz_down[(size_t)(b * MM + mc) * 3 + tid];
        {
            const float4* f0 = (const float4*)(feat_down + (size_t)(b * MM + mc + sm) * DD + sd);
            const float4* f1 = (const float4*)(feat_down + (size_t)(b * MM + mc + sm + 1) * DD + sd);
            float4 a0 = f0[0], a1 = f0[1];
            float4 b0 = f1[0], b1 = f1[1];
            float r0[8] = {a0.x, a0.y, a0.z, a0.w, a1.x, a1.y, a1.z, a1.w};
            float r1[8] = {b0.x, b0.y, b0.z, b0.w, b1.x, b1.y, b1.z, b1.w};
#pragma unroll
            for (int j = 0; j < 8; j++) {
                u32 pk = (u32)f2bf(r0[j]) | ((u32)f2bf(r1[j]) << 16);
                *(u32*)&ftbuf[(sd + j) * FS + sm] = pk;
            }
        }
        __syncthreads();
        {
            float dlc = 0.f;
#pragma unroll
            for (int s = 0; s < 4; s++) {
                bf16x8 v;
#pragma unroll
                for (int j = 0; j < 8; j++) {
                    int m = half * 32 + s * 8 + j;
                    float dx = ax - xyzb[3 * m + 0];
                    float dy = ay - xyzb[3 * m + 1];
                    float dz = az - xyzb[3 * m + 2];
                    float d = fmaf(dx, dx, fmaf(dy, dy, dz * dz)) + 1e-8f;
                    float r = __builtin_amdgcn_rcpf(d);
                    dlc += r;
                    v[j] = (short)f2bf(r);
                }
                *(bf16x8*)&rbuf[nl_r * RS + half * 32 + s * 8] = v;
            }
            denp[nl_r * 2 + half] += dlc;
        }
        __syncthreads();
        {
            const int rowbase = wave * 32;
#pragma unroll
            for (int k0 = 0; k0 < BM; k0 += 32) {
                bf16x8 a0 = *(bf16x8*)&rbuf[(rowbase + nl) * RS + k0 + q * 8];
                bf16x8 a1 = *(bf16x8*)&rbuf[(rowbase + 16 + nl) * RS + k0 + q * 8];
#pragma unroll
                for (int dt = 0; dt < 4; dt++) {
                    bf16x8 bb = *(bf16x8*)&ftbuf[(dt * 16 + nl) * FS + k0 + q * 8];
                    acc[0][dt] = __builtin_amdgcn_mfma_f32_16x16x32_bf16(a0, bb, acc[0][dt], 0, 0, 0);
                    acc[1][dt] = __builtin_amdgcn_mfma_f32_16x16x32_bf16(a1, bb, acc[1][dt], 0, 0, 0);
                }
            }
        }
    }

    __syncthreads();
    if (tid < TN) invden[tid] = 1.0f / (denp[tid * 2] + denp[tid * 2 + 1]);
    __syncthreads();
    {
        const int rowbase = wave * 32;
#pragma unroll
        for (int nt = 0; nt < 2; nt++) {
#pragma unroll
            for (int reg = 0; reg < 4; reg++) {
                int nloc = rowbase + nt * 16 + q * 4 + reg;
                float inv = invden[nloc];
                size_t gbase = (size_t)(b * NN + n0 + nloc) * DD;
#pragma unroll
                for (int dt = 0; dt < 4; dt++)
                    interp_out[gbase + dt * 16 + nl] = f2bf(acc[nt][dt][reg] * inv);
            }
        }
    }
}

#define T2 64

__global__ __launch_bounds__(256, 1)
void mlp_kernel(const float* __restrict__ feat_up,
                const u16*   __restrict__ interp,
                const float* __restrict__ W1, const float* __restrict__ b1,
                const float* __restrict__ g1, const float* __restrict__ be1,
                const float* __restrict__ m1, const float* __restrict__ v1,
                const float* __restrict__ W2, const float* __restrict__ b2,
                const float* __restrict__ g2, const float* __restrict__ be2,
                const float* __restrict__ m2, const float* __restrict__ v2,
                float* __restrict__ out)
{
    __shared__ u16 xb[T2 * 136];
    __shared__ u16 hb[T2 * 136];
    __shared__ u16 w1b[128 * 136];
    __shared__ u16 w2b[64 * 136];
    __shared__ float A1[128], Bc1[128], A2[64], Bc2[64];

    const int tid = threadIdx.x;
    const int b  = blockIdx.x >> 8;
    const int n0 = (blockIdx.x & 255) * T2;
    const int wave = tid >> 6;
    const int lane = tid & 63;
    const int q    = lane >> 4;
    const int nl   = lane & 15;

    if (tid < 128) {
        float a = g1[tid] * rsqrtf(v1[tid] + 1e-5f);
        A1[tid]  = a;
        Bc1[tid] = (b1[tid] - m1[tid]) * a + be1[tid];
    } else if (tid < 192) {
        int o = tid - 128;
        float a = g2[o] * rsqrtf(v2[o] + 1e-5f);
        A2[o]  = a;
        Bc2[o] = (b2[o] - m2[o]) * a + be2[o];
    }
    {
        const float4* src = (const float4*)(W1 + (size_t)(tid >> 1) * 128 + (tid & 1) * 64);
        u16* dst = &w1b[(tid >> 1) * 136 + (tid & 1) * 64];
#pragma unroll
        for (int i = 0; i < 8; i++)
            *(bf16x8*)(dst + 8 * i) = pack8(src[2 * i], src[2 * i + 1]);
    }
    {
        const float4* src = (const float4*)(W2 + (size_t)(tid >> 2) * 128 + (tid & 3) * 32);
        u16* dst = &w2b[(tid >> 2) * 136 + (tid & 3) * 32];
#pragma unroll
        for (int i = 0; i < 4; i++)
            *(bf16x8*)(dst + 8 * i) = pack8(src[2 * i], src[2 * i + 1]);
    }
    if (tid < 128) {
        int n = tid >> 1, hf = tid & 1;
        const float4* src = (const float4*)(feat_up + (size_t)(b * NN + n0 + n) * 64 + hf * 32);
        u16* dst = &xb[n * 136 + hf * 32];
#pragma unroll
        for (int i = 0; i < 4; i++)
            *(bf16x8*)(dst + 8 * i) = pack8(src[2 * i], src[2 * i + 1]);
    } else {
        int t2 = tid - 128;
        int n = t2 >> 1, hf = t2 & 1;
        const uint4* src = (const uint4*)(interp + (size_t)(b * NN + n0 + n) * 64 + hf * 32);
        u16* dst = &xb[n * 136 + 64 + hf * 32];
#pragma unroll
        for (int i = 0; i < 4; i++)
            *(uint4*)(dst + 8 * i) = src[i];
    }
    __syncthreads();

    f32x4 acc1[8];
#pragma unroll
    for (int i = 0; i < 8; i++) acc1[i] = (f32x4){0.f, 0.f, 0.f, 0.f};
#pragma unroll
    for (int k0 = 0; k0 < 128; k0 += 32) {
        bf16x8 a = *(bf16x8*)&xb[(wave * 16 + nl) * 136 + k0 + q * 8];
#pragma unroll
        for (int ot = 0; ot < 8; ot++) {
            bf16x8 bb = *(bf16x8*)&w1b[(ot * 16 + nl) * 136 + k0 + q * 8];
            acc1[ot] = __builtin_amdgcn_mfma_f32_16x16x32_bf16(a, bb, acc1[ot], 0, 0, 0);
        }
    }
#pragma unroll
    for (int ot = 0; ot < 8; ot++) {
        int o = ot * 16 + nl;
        float aa = A1[o], bc = Bc1[o];
#pragma unroll
        for (int reg = 0; reg < 4; reg++) {
            float v = fmaxf(fmaf(acc1[ot][reg], aa, bc), 0.f);
            hb[(wave * 16 + q * 4 + reg) * 136 + o] = f2bf(v);
        }
    }
    __syncthreads();

    f32x4 acc2[4];
#pragma unroll
    for (int i = 0; i < 4; i++) acc2[i] = (f32x4){0.f, 0.f, 0.f, 0.f};
#pragma unroll
    for (int k0 = 0; k0 < 128; k0 += 32) {
        bf16x8 a = *(bf16x8*)&hb[(wave * 16 + nl) * 136 + k0 + q * 8];
#pragma unroll
        for (int ot = 0; ot < 4; ot++) {
            bf16x8 bb = *(bf16x8*)&w2b[(ot * 16 + nl) * 136 + k0 + q * 8];
            acc2[ot] = __builtin_amdgcn_mfma_f32_16x16x32_bf16(a, bb, acc2[ot], 0, 0, 0);
        }
    }
#pragma unroll
    for (int ot = 0; ot < 4; ot++) {
        int o = ot * 16 + nl;
        float aa = A2[o], bc = Bc2[o];
#pragma unroll
        for (int reg = 0; reg < 4; reg++)
            out[(size_t)(b * NN + n0 + wave * 16 + q * 4 + reg) * 64 + o] =
                fmaf(acc2[ot][reg], aa, bc);
    }
}

extern "C" void kernel_launch(void* const* d_in, const int* in_sizes, int n_in,
                              void* d_out, int out_size, void* d_ws, size_t ws_size,
                              hipStream_t stream) {
    const float* xyz_down  = (const float*)d_in[0];
    const float* xyz_up    = (const float*)d_in[1];
    const float* feat_down = (const float*)d_in[2];
    const float* feat_up   = (const float*)d_in[3];
    const float* W1  = (const float*)d_in[4];
    const float* b1  = (const float*)d_in[5];
    const float* g1  = (const float*)d_in[6];
    const float* be1 = (const float*)d_in[7];
    const float* m1  = (const float*)d_in[8];
    const float* v1  = (const float*)d_in[9];
    const float* W2  = (const float*)d_in[10];
    const float* b2  = (const float*)d_in[11];
    const float* g2  = (const float*)d_in[12];
    const float* be2 = (const float*)d_in[13];
    const float* m2  = (const float*)d_in[14];
    const float* v2  = (const float*)d_in[15];
    float* out = (float*)d_out;
    char* ws = (char*)d_ws;

    if (ws_size >= WS_NEED) {
        u16*    interp = (u16*)(ws + OFF_INTERP);
        u16*    fdT    = (u16*)(ws + OFF_FDT);
        float4* xyzd2  = (float4*)(ws + OFF_XYZ);
        u16*    w1bf   = (u16*)(ws + OFF_W1);
        u16*    w2bf   = (u16*)(ws + OFF_W2);
        float*  bnbuf  = (float*)(ws + OFF_BN);

        prep3_kernel<<<dim3(173), dim3(256), 0, stream>>>(
            xyz_down, feat_down, W1, b1, g1, be1, m1, v1,
            W2, b2, g2, be2, m2, v2, fdT, xyzd2, w1bf, w2bf, bnbuf);
        interp3_kernel<<<dim3(BB * (NN / 64)), dim3(256), 0, stream>>>(
            xyz_up, fdT, xyzd2, interp);
        mlp3_kernel<<<dim3(BB * (NN / 64)), dim3(256), 0, stream>>>(
            feat_up, interp, w1bf, w2bf, bnbuf, out);
    } else {
        u16* interp = (u16*)d_ws;
        interp_kernel<<<dim3(BB * (NN / TN)), dim3(256), 0, stream>>>(
            xyz_down, xyz_up, feat_down, interp);
        mlp_kernel<<<dim3(BB * (NN / T2)), dim3(256), 0, stream>>>(
            feat_up, interp, W1, b1, g1, be1, m1, v1,
            W2, b2, g2, be2, m2, v2, out);
    }
}

// Round 5
// 156.912 us; speedup vs baseline: 1.6210x; 1.6210x over previous
//
#include <hip/hip_runtime.h>

typedef unsigned short u16;
typedef unsigned int   u32;
typedef unsigned long long u64;

typedef __attribute__((ext_vector_type(8))) short bf16x8;
typedef __attribute__((ext_vector_type(4))) float f32x4;

#define BB 4
#define MM 2048
#define NN 16384
#define DD 64

__device__ __forceinline__ u16 f2bf(float f) {
    union { float f; u32 u; } v; v.f = f;
    u32 r = v.u + 0x7fffu + ((v.u >> 16) & 1u);   // RNE
    return (u16)(r >> 16);
}

// pack two floats to bf16 pair by truncation: lo16=trunc(lo), hi16=trunc(hi)
__device__ __forceinline__ u32 pack_trunc(float hi, float lo) {
    union { float f; u32 u; } a, b; a.f = hi; b.f = lo;
    return __builtin_amdgcn_perm(a.u, b.u, 0x07060302);
}

// RNE pack of two floats into a bf16 pair
__device__ __forceinline__ u32 pack_rne(float hi, float lo) {
    return (u32)f2bf(lo) | ((u32)f2bf(hi) << 16);
}

__device__ __forceinline__ bf16x8 pack8(float4 p, float4 q) {
    bf16x8 v;
    v[0] = (short)f2bf(p.x); v[1] = (short)f2bf(p.y);
    v[2] = (short)f2bf(p.z); v[3] = (short)f2bf(p.w);
    v[4] = (short)f2bf(q.x); v[5] = (short)f2bf(q.y);
    v[6] = (short)f2bf(q.z); v[7] = (short)f2bf(q.w);
    return v;
}

// ===========================================================================
// ws layout:
//   [0, 8M)        interp bf16 [b][n][64]
//   [8M, 9M)       fdT   bf16 [b][d][m]   (feat_down transposed)
//   [9M, +128K)    xyzd2 float4 [b*M]  = (-2bx,-2by,-2bz, |b|^2+1e-8)
//   [.., +32K)     W1 bf16 [128][128]
//   [.., +16K)     W2 bf16 [64][128]
//   [.., +1.5K)    bn consts float[384] = A1[128] Bc1[128] A2[64] Bc2[64]
// ===========================================================================
#define OFF_INTERP 0ull
#define OFF_FDT    8388608ull
#define OFF_XYZ    9437184ull
#define OFF_W1     9568256ull
#define OFF_W2     9601024ull
#define OFF_BN     9617408ull
#define WS_NEED    9618944ull

// ---------------------------------------------------------------------------
// prep4: coalesced LDS-tile transpose + conversions. 173 blocks x 256.
//  blk   0..127 : feat_down transpose  (b = blk>>5, m-tile = blk&31)
//  blk 128..159 : xyzd2
//  blk 160..167 : W1 -> bf16
//  blk 168..171 : W2 -> bf16
//  blk 172      : BN fold
// ---------------------------------------------------------------------------
__global__ __launch_bounds__(256)
void prep4_kernel(const float* __restrict__ xyz_down,
                  const float* __restrict__ feat_down,
                  const float* __restrict__ W1, const float* __restrict__ b1,
                  const float* __restrict__ g1, const float* __restrict__ be1,
                  const float* __restrict__ m1, const float* __restrict__ v1,
                  const float* __restrict__ W2, const float* __restrict__ b2,
                  const float* __restrict__ g2, const float* __restrict__ be2,
                  const float* __restrict__ m2, const float* __restrict__ v2,
                  u16* __restrict__ fdT, float4* __restrict__ xyzd2,
                  u16* __restrict__ w1bf, u16* __restrict__ w2bf,
                  float* __restrict__ bnbuf)
{
    const int blk = blockIdx.x, t = threadIdx.x;
    if (blk < 128) {
        __shared__ u16 T[64 * 70];                 // [m_local][d], stride 70 (odd dwords)
        const int b = blk >> 5, m0 = (blk & 31) * 64;
        // phase A: coalesced read, convert, store to LDS rows
        {
            const int row = t >> 2, fcb = (t & 3) * 16;   // 4 threads/row, 16 cols each
            const float4* src = (const float4*)(feat_down + ((size_t)(b * MM + m0 + row)) * 64 + fcb);
#pragma unroll
            for (int i = 0; i < 4; i++) {
                float4 v = src[i];
                union { u16 h[4]; u64 q; } pk;
                pk.h[0] = f2bf(v.x); pk.h[1] = f2bf(v.y);
                pk.h[2] = f2bf(v.z); pk.h[3] = f2bf(v.w);
                *(u64*)&T[row * 70 + fcb + i * 4] = pk.q;
            }
        }
        __syncthreads();
        // phase B: d = t&63 (full bank spread, 2-way = free), m-subtile = t>>6
        {
            const int d = t & 63, w = t >> 6;
            union { u16 h[16]; uint4 q[2]; } o;
#pragma unroll
            for (int j = 0; j < 16; j++) o.h[j] = T[(w * 16 + j) * 70 + d];
            uint4* dst = (uint4*)&fdT[((size_t)(b * 64 + d)) * MM + m0 + w * 16];
            dst[0] = o.q[0];
            dst[1] = o.q[1];
        }
    } else if (blk < 160) {
        int idx = (blk - 128) * 256 + t;           // b*M + m
        float x = xyz_down[idx * 3 + 0], y = xyz_down[idx * 3 + 1], z = xyz_down[idx * 3 + 2];
        xyzd2[idx] = make_float4(-2.f * x, -2.f * y, -2.f * z,
                                 x * x + y * y + z * z + 1e-8f);
    } else if (blk < 168) {
        int g = (blk - 160) * 256 + t;             // group of 8 elems
        const float4* s = (const float4*)(W1 + g * 8);
        bf16x8 v = pack8(s[0], s[1]);
        *(bf16x8*)&w1bf[g * 8] = v;
    } else if (blk < 172) {
        int g = (blk - 168) * 256 + t;
        const float4* s = (const float4*)(W2 + g * 8);
        bf16x8 v = pack8(s[0], s[1]);
        *(bf16x8*)&w2bf[g * 8] = v;
    } else {
        if (t < 128) {
            float a = g1[t] * rsqrtf(v1[t] + 1e-5f);
            bnbuf[t] = a;
            bnbuf[128 + t] = (b1[t] - m1[t]) * a + be1[t];
        } else if (t < 192) {
            int o = t - 128;
            float a = g2[o] * rsqrtf(v2[o] + 1e-5f);
            bnbuf[256 + o] = a;
            bnbuf[320 + o] = (b2[o] - m2[o]) * a + be2[o];
        }
    }
}

// ---------------------------------------------------------------------------
// interp4: interp2 structure (LDS-staged ftbuf = proven) + single-barrier
// register-staged double buffer + denominator via MFMA-ones (lane-local).
// 1024 blocks, 4 blocks/CU (LDS 20.7 KB).
// ---------------------------------------------------------------------------
__global__ __launch_bounds__(256, 4)
void interp4_kernel(const float* __restrict__ xyz_up,
                    const u16* __restrict__ fdT,
                    const float4* __restrict__ xyzd2,
                    u16* __restrict__ interp_out)
{
    __shared__ u16    ftbuf[2][64 * 72];   // feat^T chunk [d][m], stride 72
    __shared__ float4 xyzb[2][72];         // swizzled: idx = m + (m>>3)

    const int tid = threadIdx.x;
    const int b  = blockIdx.x >> 8;
    const int n0 = (blockIdx.x & 255) * 64;
    const int wave = tid >> 6;
    const int lane = tid & 63;
    const int q    = lane >> 4;
    const int nl   = lane & 15;

    const int row = n0 + wave * 16 + nl;
    const float* xu = xyz_up + ((size_t)(b * NN + row)) * 3;
    const float ax = xu[0], ay = xu[1], az = xu[2];
    const float a2 = ax * ax + ay * ay + az * az;

    f32x4 acc[4];
#pragma unroll
    for (int i = 0; i < 4; i++) acc[i] = (f32x4){0.f, 0.f, 0.f, 0.f};
    f32x4 accd = (f32x4){0.f, 0.f, 0.f, 0.f};

    bf16x8 ones;
#pragma unroll
    for (int i = 0; i < 8; i++) ones[i] = (short)0x3F80;   // bf16 1.0

    // staging identity: thread covers (d = tid>>2, 32B of m)
    const int sd = tid >> 2, sms = (tid & 3) * 16;
    const u16* fsrc = fdT + ((size_t)(b * 64 + sd)) * MM + sms;
    const float4* xsrc = xyzd2 + b * MM;

    // prologue: stage chunk 0
    {
        u16* fd = &ftbuf[0][sd * 72 + sms];
        *(uint4*)fd       = *(const uint4*)(fsrc);
        *(uint4*)(fd + 8) = *(const uint4*)(fsrc + 8);
        if (tid < 64) xyzb[0][tid + (tid >> 3)] = xsrc[tid];
    }
    __syncthreads();

    for (int c = 0; c < 32; ++c) {
        const int cur = c & 1, nxt = cur ^ 1;
        const bool have_next = (c + 1) < 32;
        uint4 nf0, nf1; float4 nx;
        if (have_next) {
            const int mc = (c + 1) * 64;
            nf0 = *(const uint4*)(fsrc + mc);
            nf1 = *(const uint4*)(fsrc + mc + 8);
            if (tid < 64) nx = xsrc[mc + tid];
        }

        // compute chunk c from buffers [cur]
#pragma unroll
        for (int kk = 0; kk < 2; kk++) {
            u32 fr[4];
#pragma unroll
            for (int jp = 0; jp < 4; jp++) {
                int m0 = kk * 32 + q * 8 + jp * 2;
                int s0 = m0 + (m0 >> 3);           // m0,m0+1 share the 8-group
                float4 p0 = xyzb[cur][s0];         // 16-lane broadcast reads
                float4 p1 = xyzb[cur][s0 + 1];
                float d0 = fmaf(p0.x, ax, fmaf(p0.y, ay, fmaf(p0.z, az, p0.w + a2)));
                float d1 = fmaf(p1.x, ax, fmaf(p1.y, ay, fmaf(p1.z, az, p1.w + a2)));
                d0 = fmaxf(d0, 1e-8f);             // guard fp32 cancellation
                d1 = fmaxf(d1, 1e-8f);
                float r0 = __builtin_amdgcn_rcpf(d0);
                float r1 = __builtin_amdgcn_rcpf(d1);
                fr[jp] = pack_trunc(r1, r0);
            }
            union { u32 u[4]; bf16x8 v; } af;
            af.u[0] = fr[0]; af.u[1] = fr[1]; af.u[2] = fr[2]; af.u[3] = fr[3];
#pragma unroll
            for (int dt = 0; dt < 4; dt++) {
                bf16x8 bb = *(bf16x8*)&ftbuf[cur][(dt * 16 + nl) * 72 + kk * 32 + q * 8];
                acc[dt] = __builtin_amdgcn_mfma_f32_16x16x32_bf16(af.v, bb, acc[dt], 0, 0, 0);
            }
            // den: row-sum of the SAME truncated r (ones B-frag) -> bias cancels
            accd = __builtin_amdgcn_mfma_f32_16x16x32_bf16(af.v, ones, accd, 0, 0, 0);
        }

        if (have_next) {
            u16* fd = &ftbuf[nxt][sd * 72 + sms];
            *(uint4*)fd       = nf0;
            *(uint4*)(fd + 8) = nf1;
            if (tid < 64) xyzb[nxt][tid + (tid >> 3)] = nx;
        }
        __syncthreads();
    }

    // epilogue: accd[reg] = den of row q*4+reg (lane-local, no reduction)
#pragma unroll
    for (int reg = 0; reg < 4; reg++) {
        int r = wave * 16 + q * 4 + reg;
        float inv = 1.0f / accd[reg];
        size_t gbase = ((size_t)(b * NN + n0 + r)) * 64;
#pragma unroll
        for (int dt = 0; dt < 4; dt++)
            interp_out[gbase + dt * 16 + nl] = f2bf(acc[dt][reg] * inv);
    }
}

// ---------------------------------------------------------------------------
// mlp4: 512 blocks x 2 n-tiles. Weights+BN staged to LDS ONCE per block;
// x staged coalesced; x/h/out share one wave-private-slab LDS buffer
// (stride 272B in all three views); coalesced float4 out stores.
// LDS 71 KB -> 2 blocks/CU.
// ---------------------------------------------------------------------------
__global__ __launch_bounds__(256, 2)
void mlp4_kernel(const float* __restrict__ feat_up,
                 const u16* __restrict__ interp,
                 const u16* __restrict__ w1bf,
                 const u16* __restrict__ w2bf,
                 const float* __restrict__ bnbuf,
                 float* __restrict__ out)
{
    __shared__ u16   w1L[128 * 136];   // 34816 B
    __shared__ u16   w2L[64 * 136];    // 17408 B
    __shared__ u16   xh[64 * 136];     // 17408 B (x tile, then h tile, then f32 out tile @ stride 68 dwords)
    __shared__ float bnl[384];         //  1536 B   total 71168 -> 2 blocks/CU

    const int tid = threadIdx.x;
    const int b    = blockIdx.x >> 7;
    const int base = (blockIdx.x & 127) * 128;
    const int wave = tid >> 6;
    const int lane = tid & 63;
    const int q    = lane >> 4;
    const int nl   = lane & 15;

    bnl[tid] = bnbuf[tid];
    if (tid < 128) bnl[256 + tid] = bnbuf[256 + tid];

    // stage W1 (thread = half-row) and W2 (thread = quarter-row), once
    {
        const int o = tid >> 1, h = (tid & 1) * 64;
        const uint4* src = (const uint4*)(w1bf + (size_t)o * 128 + h);
        uint4* dst = (uint4*)&w1L[o * 136 + h];
#pragma unroll
        for (int i = 0; i < 8; i++) dst[i] = src[i];
    }
    {
        const int o = tid >> 2, h = (tid & 3) * 32;
        const uint4* src = (const uint4*)(w2bf + (size_t)o * 128 + h);
        uint4* dst = (uint4*)&w2L[o * 136 + h];
#pragma unroll
        for (int i = 0; i < 4; i++) dst[i] = src[i];
    }

    for (int tile = 0; tile < 2; tile++) {
        const int n0 = base + tile * 64;
        __syncthreads();   // previous tile's xh reads done; safe to overwrite

        // stage x = [feat_up bf16 | interp] coalesced: thread = (row, 16-ch seg)
        {
            const int r = tid >> 2, seg = (tid & 3) * 16;
            const float4* fs = (const float4*)(feat_up + ((size_t)(b * NN + n0 + r)) * 64 + seg);
            uint4* xd = (uint4*)&xh[r * 136 + seg];
            float4 f0 = fs[0], f1 = fs[1], f2 = fs[2], f3 = fs[3];
            uint4 o0, o1;
            o0.x = pack_rne(f0.y, f0.x); o0.y = pack_rne(f0.w, f0.z);
            o0.z = pack_rne(f1.y, f1.x); o0.w = pack_rne(f1.w, f1.z);
            o1.x = pack_rne(f2.y, f2.x); o1.y = pack_rne(f2.w, f2.z);
            o1.z = pack_rne(f3.y, f3.x); o1.w = pack_rne(f3.w, f3.z);
            xd[0] = o0; xd[1] = o1;
            const uint4* is = (const uint4*)(interp + ((size_t)(b * NN + n0 + r)) * 64 + seg);
            uint4* xd2 = (uint4*)&xh[r * 136 + 64 + seg];
            xd2[0] = is[0]; xd2[1] = is[1];
        }
        __syncthreads();

        // GEMM1: 64x128 @ 128
        f32x4 acc1[8];
#pragma unroll
        for (int i = 0; i < 8; i++) acc1[i] = (f32x4){0.f, 0.f, 0.f, 0.f};
#pragma unroll
        for (int k0 = 0; k0 < 128; k0 += 32) {
            bf16x8 af = *(bf16x8*)&xh[(wave * 16 + nl) * 136 + k0 + q * 8];
#pragma unroll
            for (int ot = 0; ot < 8; ot++) {
                bf16x8 bf = *(bf16x8*)&w1L[(ot * 16 + nl) * 136 + k0 + q * 8];
                acc1[ot] = __builtin_amdgcn_mfma_f32_16x16x32_bf16(af, bf, acc1[ot], 0, 0, 0);
            }
        }
        __syncthreads();   // all xh(x) reads done before h overwrite

        // BN1 + ReLU -> bf16 hidden into xh (A-layout)
#pragma unroll
        for (int ot = 0; ot < 8; ot++) {
            int o = ot * 16 + nl;
            float aa = bnl[o], bc = bnl[128 + o];
#pragma unroll
            for (int reg = 0; reg < 4; reg++) {
                float v = fmaxf(fmaf(acc1[ot][reg], aa, bc), 0.f);
                xh[(wave * 16 + q * 4 + reg) * 136 + o] = f2bf(v);
            }
        }
        __syncthreads();

        // GEMM2: 64x128 -> 64
        f32x4 acc2[4];
#pragma unroll
        for (int i = 0; i < 4; i++) acc2[i] = (f32x4){0.f, 0.f, 0.f, 0.f};
#pragma unroll
        for (int k0 = 0; k0 < 128; k0 += 32) {
            bf16x8 af = *(bf16x8*)&xh[(wave * 16 + nl) * 136 + k0 + q * 8];
#pragma unroll
            for (int ot = 0; ot < 4; ot++) {
                bf16x8 bf = *(bf16x8*)&w2L[(ot * 16 + nl) * 136 + k0 + q * 8];
                acc2[ot] = __builtin_amdgcn_mfma_f32_16x16x32_bf16(af, bf, acc2[ot], 0, 0, 0);
            }
        }
        // BN2 -> f32 tile in xh (stride 68 dwords = 272B = same row offsets ->
        // wave-private 16-row slab, no barrier needed vs this wave's h reads)
        float* of = (float*)xh;
#pragma unroll
        for (int ot = 0; ot < 4; ot++) {
            int o = ot * 16 + nl;
            float aa = bnl[256 + o], bc = bnl[320 + o];
#pragma unroll
            for (int reg = 0; reg < 4; reg++)
                of[(wave * 16 + q * 4 + reg) * 68 + o] = fmaf(acc2[ot][reg], aa, bc);
        }
        __syncthreads();   // cross-wave: copy threads read other waves' slabs

        // coalesced out store: thread = (row, 16-dword seg)
        {
            const int r = tid >> 2, seg = (tid & 3) * 16;
            const float4* sf = (const float4*)&of[r * 68 + seg];
            float4* dst = (float4*)(out + ((size_t)(b * NN + n0 + r)) * 64 + seg);
#pragma unroll
            for (int i = 0; i < 4; i++) dst[i] = sf[i];
        }
    }
}

// ===========================================================================
// Fallback (round-1 kernels, proven): used when ws_size < WS_NEED.
// ===========================================================================
#define TN 128
#define BM 64
#define RS 72
#define FS 72

__global__ __launch_bounds__(256, 3)
void interp_kernel(const float* __restrict__ xyz_down,
                   const float* __restrict__ xyz_up,
                   const float* __restrict__ feat_down,
                   u16* __restrict__ interp_out)
{
    __shared__ u16   rbuf[TN * RS];
    __shared__ u16   ftbuf[DD * FS];
    __shared__ float xyzb[BM * 3];
    __shared__ float denp[TN * 2];
    __shared__ float invden[TN];

    const int tid = threadIdx.x;
    const int b  = blockIdx.x >> 7;
    const int n0 = (blockIdx.x & 127) * TN;

    const int nl_r = tid >> 1;
    const int half = tid & 1;
    const float* xu = xyz_up + (size_t)(b * NN + n0 + nl_r) * 3;
    const float ax = xu[0], ay = xu[1], az = xu[2];

    denp[tid] = 0.f;

    const int wave = tid >> 6;
    const int lane = tid & 63;
    const int q    = lane >> 4;
    const int nl   = lane & 15;

    f32x4 acc[2][4];
#pragma unroll
    for (int i = 0; i < 2; i++)
#pragma unroll
        for (int j = 0; j < 4; j++) acc[i][j] = (f32x4){0.f, 0.f, 0.f, 0.f};

    const int sm = (tid & 31) * 2;
    const int sd = (tid >> 5) * 8;

    for (int mc = 0; mc < MM; mc += BM) {
        __syncthreads();
        if (tid < 192) xyzb[tid] = xyz_down[(size_t)(b * MM + mc) * 3 + tid];
        {
            const float4* f0 = (const float4*)(feat_down + (size_t)(b * MM + mc + sm) * DD + sd);
            const float4* f1 = (const float4*)(feat_down + (size_t)(b * MM + mc + sm + 1) * DD + sd);
            float4 a0 = f0[0], a1 = f0[1];
            float4 b0 = f1[0], b1 = f1[1];
            float r0[8] = {a0.x, a0.y, a0.z, a0.w, a1.x, a1.y, a1.z, a1.w};
            float r1[8] = {b0.x, b0.y, b0.z, b0.w, b1.x, b1.y, b1.z, b1.w};
#pragma unroll
            for (int j = 0; j < 8; j++) {
                u32 pk = (u32)f2bf(r0[j]) | ((u32)f2bf(r1[j]) << 16);
                *(u32*)&ftbuf[(sd + j) * FS + sm] = pk;
            }
        }
        __syncthreads();
        {
            float dlc = 0.f;
#pragma unroll
            for (int s = 0; s < 4; s++) {
                bf16x8 v;
#pragma unroll
                for (int j = 0; j < 8; j++) {
                    int m = half * 32 + s * 8 + j;
                    float dx = ax - xyzb[3 * m + 0];
                    float dy = ay - xyzb[3 * m + 1];
                    float dz = az - xyzb[3 * m + 2];
                    float d = fmaf(dx, dx, fmaf(dy, dy, dz * dz)) + 1e-8f;
                    float r = __builtin_amdgcn_rcpf(d);
                    dlc += r;
                    v[j] = (short)f2bf(r);
                }
                *(bf16x8*)&rbuf[nl_r * RS + half * 32 + s * 8] = v;
            }
            denp[nl_r * 2 + half] += dlc;
        }
        __syncthreads();
        {
            const int rowbase = wave * 32;
#pragma unroll
            for (int k0 = 0; k0 < BM; k0 += 32) {
                bf16x8 a0 = *(bf16x8*)&rbuf[(rowbase + nl) * RS + k0 + q * 8];
                bf16x8 a1 = *(bf16x8*)&rbuf[(rowbase + 16 + nl) * RS + k0 + q * 8];
#pragma unroll
                for (int dt = 0; dt < 4; dt++) {
                    bf16x8 bb = *(bf16x8*)&ftbuf[(dt * 16 + nl) * FS + k0 + q * 8];
                    acc[0][dt] = __builtin_amdgcn_mfma_f32_16x16x32_bf16(a0, bb, acc[0][dt], 0, 0, 0);
                    acc[1][dt] = __builtin_amdgcn_mfma_f32_16x16x32_bf16(a1, bb, acc[1][dt], 0, 0, 0);
                }
            }
        }
    }

    __syncthreads();
    if (tid < TN) invden[tid] = 1.0f / (denp[tid * 2] + denp[tid * 2 + 1]);
    __syncthreads();
    {
        const int rowbase = wave * 32;
#pragma unroll
        for (int nt = 0; nt < 2; nt++) {
#pragma unroll
            for (int reg = 0; reg < 4; reg++) {
                int nloc = rowbase + nt * 16 + q * 4 + reg;
                float inv = invden[nloc];
                size_t gbase = (size_t)(b * NN + n0 + nloc) * DD;
#pragma unroll
                for (int dt = 0; dt < 4; dt++)
                    interp_out[gbase + dt * 16 + nl] = f2bf(acc[nt][dt][reg] * inv);
            }
        }
    }
}

#define T2 64

__global__ __launch_bounds__(256, 1)
void mlp_kernel(const float* __restrict__ feat_up,
                const u16*   __restrict__ interp,
                const float* __restrict__ W1, const float* __restrict__ b1,
                const float* __restrict__ g1, const float* __restrict__ be1,
                const float* __restrict__ m1, const float* __restrict__ v1,
                const float* __restrict__ W2, const float* __restrict__ b2,
                const float* __restrict__ g2, const float* __restrict__ be2,
                const float* __restrict__ m2, const float* __restrict__ v2,
                float* __restrict__ out)
{
    __shared__ u16 xb[T2 * 136];
    __shared__ u16 hb[T2 * 136];
    __shared__ u16 w1b[128 * 136];
    __shared__ u16 w2b[64 * 136];
    __shared__ float A1[128], Bc1[128], A2[64], Bc2[64];

    const int tid = threadIdx.x;
    const int b  = blockIdx.x >> 8;
    const int n0 = (blockIdx.x & 255) * T2;
    const int wave = tid >> 6;
    const int lane = tid & 63;
    const int q    = lane >> 4;
    const int nl   = lane & 15;

    if (tid < 128) {
        float a = g1[tid] * rsqrtf(v1[tid] + 1e-5f);
        A1[tid]  = a;
        Bc1[tid] = (b1[tid] - m1[tid]) * a + be1[tid];
    } else if (tid < 192) {
        int o = tid - 128;
        float a = g2[o] * rsqrtf(v2[o] + 1e-5f);
        A2[o]  = a;
        Bc2[o] = (b2[o] - m2[o]) * a + be2[o];
    }
    {
        const float4* src = (const float4*)(W1 + (size_t)(tid >> 1) * 128 + (tid & 1) * 64);
        u16* dst = &w1b[(tid >> 1) * 136 + (tid & 1) * 64];
#pragma unroll
        for (int i = 0; i < 8; i++)
            *(bf16x8*)(dst + 8 * i) = pack8(src[2 * i], src[2 * i + 1]);
    }
    {
        const float4* src = (const float4*)(W2 + (size_t)(tid >> 2) * 128 + (tid & 3) * 32);
        u16* dst = &w2b[(tid >> 2) * 136 + (tid & 3) * 32];
#pragma unroll
        for (int i = 0; i < 4; i++)
            *(bf16x8*)(dst + 8 * i) = pack8(src[2 * i], src[2 * i + 1]);
    }
    if (tid < 128) {
        int n = tid >> 1, hf = tid & 1;
        const float4* src = (const float4*)(feat_up + (size_t)(b * NN + n0 + n) * 64 + hf * 32);
        u16* dst = &xb[n * 136 + hf * 32];
#pragma unroll
        for (int i = 0; i < 4; i++)
            *(bf16x8*)(dst + 8 * i) = pack8(src[2 * i], src[2 * i + 1]);
    } else {
        int t2 = tid - 128;
        int n = t2 >> 1, hf = t2 & 1;
        const uint4* src = (const uint4*)(interp + (size_t)(b * NN + n0 + n) * 64 + hf * 32);
        u16* dst = &xb[n * 136 + 64 + hf * 32];
#pragma unroll
        for (int i = 0; i < 4; i++)
            *(uint4*)(dst + 8 * i) = src[i];
    }
    __syncthreads();

    f32x4 acc1[8];
#pragma unroll
    for (int i = 0; i < 8; i++) acc1[i] = (f32x4){0.f, 0.f, 0.f, 0.f};
#pragma unroll
    for (int k0 = 0; k0 < 128; k0 += 32) {
        bf16x8 a = *(bf16x8*)&xb[(wave * 16 + nl) * 136 + k0 + q * 8];
#pragma unroll
        for (int ot = 0; ot < 8; ot++) {
            bf16x8 bb = *(bf16x8*)&w1b[(ot * 16 + nl) * 136 + k0 + q * 8];
            acc1[ot] = __builtin_amdgcn_mfma_f32_16x16x32_bf16(a, bb, acc1[ot], 0, 0, 0);
        }
    }
#pragma unroll
    for (int ot = 0; ot < 8; ot++) {
        int o = ot * 16 + nl;
        float aa = A1[o], bc = Bc1[o];
#pragma unroll
        for (int reg = 0; reg < 4; reg++) {
            float v = fmaxf(fmaf(acc1[ot][reg], aa, bc), 0.f);
            hb[(wave * 16 + q * 4 + reg) * 136 + o] = f2bf(v);
        }
    }
    __syncthreads();

    f32x4 acc2[4];
#pragma unroll
    for (int i = 0; i < 4; i++) acc2[i] = (f32x4){0.f, 0.f, 0.f, 0.f};
#pragma unroll
    for (int k0 = 0; k0 < 128; k0 += 32) {
        bf16x8 a = *(bf16x8*)&hb[(wave * 16 + nl) * 136 + k0 + q * 8];
#pragma unroll
        for (int ot = 0; ot < 4; ot++) {
            bf16x8 bb = *(bf16x8*)&w2b[(ot * 16 + nl) * 136 + k0 + q * 8];
            acc2[ot] = __builtin_amdgcn_mfma_f32_16x16x32_bf16(a, bb, acc2[ot], 0, 0, 0);
        }
    }
#pragma unroll
    for (int ot = 0; ot < 4; ot++) {
        int o = ot * 16 + nl;
        float aa = A2[o], bc = Bc2[o];
#pragma unroll
        for (int reg = 0; reg < 4; reg++)
            out[(size_t)(b * NN + n0 + wave * 16 + q * 4 + reg) * 64 + o] =
                fmaf(acc2[ot][reg], aa, bc);
    }
}

extern "C" void kernel_launch(void* const* d_in, const int* in_sizes, int n_in,
                              void* d_out, int out_size, void* d_ws, size_t ws_size,
                              hipStream_t stream) {
    const float* xyz_down  = (const float*)d_in[0];
    const float* xyz_up    = (const float*)d_in[1];
    const float* feat_down = (const float*)d_in[2];
    const float* feat_up   = (const float*)d_in[3];
    const float* W1  = (const float*)d_in[4];
    const float* b1  = (const float*)d_in[5];
    const float* g1  = (const float*)d_in[6];
    const float* be1 = (const float*)d_in[7];
    const float* m1  = (const float*)d_in[8];
    const float* v1  = (const float*)d_in[9];
    const float* W2  = (const float*)d_in[10];
    const float* b2  = (const float*)d_in[11];
    const float* g2  = (const float*)d_in[12];
    const float* be2 = (const float*)d_in[13];
    const float* m2  = (const float*)d_in[14];
    const float* v2  = (const float*)d_in[15];
    float* out = (float*)d_out;
    char* ws = (char*)d_ws;

    if (ws_size >= WS_NEED) {
        u16*    interp = (u16*)(ws + OFF_INTERP);
        u16*    fdT    = (u16*)(ws + OFF_FDT);
        float4* xyzd2  = (float4*)(ws + OFF_XYZ);
        u16*    w1bf   = (u16*)(ws + OFF_W1);
        u16*    w2bf   = (u16*)(ws + OFF_W2);
        float*  bnbuf  = (float*)(ws + OFF_BN);

        prep4_kernel<<<dim3(173), dim3(256), 0, stream>>>(
            xyz_down, feat_down, W1, b1, g1, be1, m1, v1,
            W2, b2, g2, be2, m2, v2, fdT, xyzd2, w1bf, w2bf, bnbuf);
        interp4_kernel<<<dim3(BB * (NN / 64)), dim3(256), 0, stream>>>(
            xyz_up, fdT, xyzd2, interp);
        mlp4_kernel<<<dim3(BB * (NN / 128)), dim3(256), 0, stream>>>(
            feat_up, interp, w1bf, w2bf, bnbuf, out);
    } else {
        u16* interp = (u16*)d_ws;
        interp_kernel<<<dim3(BB * (NN / TN)), dim3(256), 0, stream>>>(
            xyz_down, xyz_up, feat_down, interp);
        mlp_kernel<<<dim3(BB * (NN / T2)), dim3(256), 0, stream>>>(
            feat_up, interp, W1, b1, g1, be1, m1, v1,
            W2, b2, g2, be2, m2, v2, out);
    }
}